// Round 1
// baseline (231.933 us; speedup 1.0000x reference)
//
#include <hip/hip_runtime.h>
#include <stdint.h>

#define NPRED 2048
#define MT    512
#define BLK   256
#define BIGC  5000.0f

__global__ __launch_bounds__(BLK) void loss_kernel(const float* __restrict__ preds,
                                                   const float* __restrict__ targets,
                                                   double* __restrict__ acc) {
  const int b = blockIdx.x;
  const float* __restrict__ P = preds   + (size_t)b * NPRED * 5;
  const float* __restrict__ T = targets + (size_t)b * MT * 5;

  __shared__ uint64_t keys[NPRED];                    // 16 KB
  __shared__ float tgx[MT], tgy[MT], tga[MT], tgb[MT]; // 8 KB
  __shared__ float spx[MT], spy[MT], spa[MT], spb[MT]; // 8 KB
  __shared__ int s_npos, s_ntargs, s_first;
  __shared__ double red[5][BLK];                      // 10 KB

  const int tid = threadIdx.x;

  if (tid == 0) { s_npos = 0; s_ntargs = 0; s_first = 0; }
  __syncthreads();

  // ---- build sort keys + n_pos count ----
  int cpos = 0;
  for (int i = tid; i < NPRED; i += BLK) {
    float c = P[i * 5 + 0];
    cpos += (c > 0.5f) ? 1 : 0;
    uint32_t ub = ~__float_as_uint(c);   // monotone-decreasing map (c >= 0)
    keys[i] = ((uint64_t)ub << 32) | (uint32_t)i;
  }
  atomicAdd(&s_npos, cpos);

  // ---- stage targets, n_targs count ----
  int ct = 0;
  for (int m = tid; m < MT; m += BLK) {
    float tp = T[m * 5 + 0];
    ct += (tp == 1.0f) ? 1 : 0;
    tgx[m] = T[m * 5 + 1];
    tgy[m] = T[m * 5 + 2];
    tga[m] = T[m * 5 + 3];
    tgb[m] = T[m * 5 + 4];
  }
  atomicAdd(&s_ntargs, ct);
  __syncthreads();
  const int n_pos = s_npos;
  const int n_targs = s_ntargs;

  // ---- bitonic sort ascending: key asc == conf desc, ties by index asc ----
  for (int k = 2; k <= NPRED; k <<= 1) {
    for (int j = k >> 1; j > 0; j >>= 1) {
      __syncthreads();
      for (int i = tid; i < NPRED; i += BLK) {
        int ixj = i ^ j;
        if (ixj > i) {
          uint64_t a = keys[i], c2 = keys[ixj];
          bool up = ((i & k) == 0);
          if ((a > c2) == up) { keys[i] = c2; keys[ixj] = a; }
        }
      }
    }
  }
  __syncthreads();

  // ---- stage sorted-pred rows for i < n_targs ----
  for (int i = tid; i < n_targs; i += BLK) {
    int idx = (int)(keys[i] & 0xFFFFFFFFu);
    spx[i] = P[idx * 5 + 1];
    spy[i] = P[idx * 5 + 2];
    spa[i] = P[idx * 5 + 3];
    spb[i] = P[idx * 5 + 4];
  }

  // ---- prob loss over all preds (t = 1 iff sorted pos < n_targs) ----
  float accp = 0.f;
  for (int i = tid; i < NPRED; i += BLK) {
    uint32_t ub = (uint32_t)(keys[i] >> 32);
    float p = __uint_as_float(~ub);
    float term = (i < n_targs) ? -fmaxf(logf(p), -100.0f)
                               : -fmaxf(log1pf(-p), -100.0f);
    accp += term;
  }
  __syncthreads();  // spx/spy staged before wave-0 match loop

  // ---- greedy matching: wave 0 only, targets in registers ----
  float accx = 0.f, accy = 0.f, acca = 0.f, accb = 0.f;
  const int K = min(n_pos, n_targs);
  if (tid < 64) {
    const int lane = tid;
    float txr[8], tyr[8];
    uint32_t validm = 0, used = 0;
#pragma unroll
    for (int j = 0; j < 8; ++j) {
      int t = lane * 8 + j;
      txr[j] = tgx[t];
      tyr[j] = tgy[t];
      if (T[t * 5 + 0] == 1.0f) validm |= (1u << j);
    }
    for (int i = 0; i < K; ++i) {
      float x = spx[i], y = spy[i];
      uint64_t kk[8];
#pragma unroll
      for (int j = 0; j < 8; ++j) {
        bool u = (used >> j) & 1;
        bool v = (validm >> j) & 1;
        float tx = u ? BIGC : txr[j];
        float ty = u ? BIGC : tyr[j];
        float dx = __fsub_rn(tx, x), dy = __fsub_rn(ty, y);
        float d2 = __fadd_rn(__fmul_rn(dx, dx), __fmul_rn(dy, dy));
        uint32_t db = v ? __float_as_uint(d2) : 0x7F800000u; // inf if invalid
        kk[j] = ((uint64_t)db << 32) | (uint32_t)(lane * 8 + j);
      }
      // in-lane tree min
      uint64_t m01 = kk[0] < kk[1] ? kk[0] : kk[1];
      uint64_t m23 = kk[2] < kk[3] ? kk[2] : kk[3];
      uint64_t m45 = kk[4] < kk[5] ? kk[4] : kk[5];
      uint64_t m67 = kk[6] < kk[7] ? kk[6] : kk[7];
      uint64_t m03 = m01 < m23 ? m01 : m23;
      uint64_t m47 = m45 < m67 ? m45 : m67;
      uint64_t best = m03 < m47 ? m03 : m47;
      // cross-lane min (6-step butterfly)
#pragma unroll
      for (int off = 32; off; off >>= 1) {
        uint64_t o = (uint64_t)__shfl_xor((unsigned long long)best, off, 64);
        best = o < best ? o : best;
      }
      int m = (int)(best & 0xFFFFFFFFu);
      if ((m >> 3) == lane) used |= 1u << (m & 7);
      if (lane == 0) {
        float dx = __fsub_rn(spx[i], tgx[m]);
        float dy = __fsub_rn(spy[i], tgy[m]);
        float da = __fsub_rn(spa[i], tga[m]);
        float db_ = __fsub_rn(spb[i], tgb[m]);
        accx += dx * dx; accy += dy * dy; acca += da * da; accb += db_ * db_;
      }
    }
    // first valid unused target (for case_first window)
    uint32_t fi = 0xFFFFFFFFu;
#pragma unroll
    for (int j = 0; j < 8; ++j) {
      if (((validm >> j) & 1) && !((used >> j) & 1))
        fi = min(fi, (uint32_t)(lane * 8 + j));
    }
#pragma unroll
    for (int off = 32; off; off >>= 1)
      fi = min(fi, (uint32_t)__shfl_xor(fi, off, 64));
    if (lane == 0) s_first = (int)fi;
  }
  __syncthreads();

  // ---- case_first window [n_pos, n_targs) ----
  if (n_pos < n_targs) {
    int f = s_first;
    if (f >= 0 && f < MT) {
      float fx = tgx[f], fy = tgy[f], fa = tga[f], fb = tgb[f];
      for (int i = n_pos + tid; i < n_targs; i += BLK) {
        float dx = __fsub_rn(spx[i], fx);
        float dy = __fsub_rn(spy[i], fy);
        float da = __fsub_rn(spa[i], fa);
        float db_ = __fsub_rn(spb[i], fb);
        accx += dx * dx; accy += dy * dy; acca += da * da; accb += db_ * db_;
      }
    }
  }

  // ---- block reduce (doubles) + global atomic ----
  red[0][tid] = (double)accx;
  red[1][tid] = (double)accy;
  red[2][tid] = (double)acca;
  red[3][tid] = (double)accb;
  red[4][tid] = (double)accp;
  __syncthreads();
  for (int s = BLK / 2; s > 0; s >>= 1) {
    if (tid < s) {
#pragma unroll
      for (int c = 0; c < 5; ++c) red[c][tid] += red[c][tid + s];
    }
    __syncthreads();
  }
  if (tid == 0) {
#pragma unroll
    for (int c = 0; c < 5; ++c) atomicAdd(&acc[c], red[c][0]);
  }
}

__global__ void finalize_kernel(const double* __restrict__ acc,
                                float* __restrict__ out, double inv) {
  int c = threadIdx.x;
  if (c < 5) out[c] = (float)(acc[c] * inv);
}

extern "C" void kernel_launch(void* const* d_in, const int* in_sizes, int n_in,
                              void* d_out, int out_size, void* d_ws, size_t ws_size,
                              hipStream_t stream) {
  const float* preds = (const float*)d_in[0];
  const float* targets = (const float*)d_in[1];
  int B = in_sizes[0] / (NPRED * 5);

  double* acc = (double*)d_ws;
  hipMemsetAsync(acc, 0, 5 * sizeof(double), stream);
  loss_kernel<<<B, BLK, 0, stream>>>(preds, targets, acc);
  finalize_kernel<<<1, 64, 0, stream>>>(acc, (float*)d_out,
                                        1.0 / ((double)B * NPRED));
}

// Round 2
// 122.479 us; speedup vs baseline: 1.8937x; 1.8937x over previous
//
#include <hip/hip_runtime.h>
#include <stdint.h>

#define NPRED 2048
#define MT    512
#define BLK   256
#define NCAND 512

template<int C>
__device__ __forceinline__ float dppminf(float v) {
  int o = __builtin_amdgcn_update_dpp(__float_as_int(v), __float_as_int(v), C, 0xF, 0xF, false);
  float f = __int_as_float(o);
  return fminf(v, f);
}
template<int C>
__device__ __forceinline__ uint32_t dppminu(uint32_t v) {
  uint32_t o = (uint32_t)__builtin_amdgcn_update_dpp((int)v, (int)v, C, 0xF, 0xF, false);
  return v < o ? v : o;
}

// full-wave64 f32 min -> broadcast to all lanes
__device__ __forceinline__ float wave_min_f32(float v) {
  v = dppminf<0x111>(v);  // row_shr:1
  v = dppminf<0x112>(v);  // row_shr:2
  v = dppminf<0x114>(v);  // row_shr:4
  v = dppminf<0x118>(v);  // row_shr:8
  v = dppminf<0x142>(v);  // bcast15
  v = dppminf<0x143>(v);  // bcast31
  return __int_as_float(__builtin_amdgcn_readlane(__float_as_int(v), 63));
}
__device__ __forceinline__ uint32_t wave_min_u32(uint32_t v) {
  v = dppminu<0x111>(v);
  v = dppminu<0x112>(v);
  v = dppminu<0x114>(v);
  v = dppminu<0x118>(v);
  v = dppminu<0x142>(v);
  v = dppminu<0x143>(v);
  return (uint32_t)__builtin_amdgcn_readlane((int)v, 63);
}

__global__ __launch_bounds__(BLK) void loss_kernel(const float* __restrict__ preds,
                                                   const float* __restrict__ targets,
                                                   double* __restrict__ acc) {
  const int b = blockIdx.x;
  const float* __restrict__ P = preds   + (size_t)b * NPRED * 5;
  const float* __restrict__ T = targets + (size_t)b * MT * 5;

  __shared__ uint64_t keys[NPRED];                     // 16 KB
  __shared__ uint64_t cand[NCAND];                     // 4 KB
  __shared__ float tgx[MT], tgy[MT], tga[MT], tgb[MT]; // 8 KB
  __shared__ float spx[MT], spy[MT], spa[MT], spb[MT]; // 8 KB
  __shared__ int hist[256];                            // 1 KB
  __shared__ uint32_t validw[16];
  __shared__ int s_npos, s_ntargs, s_first, s_B, s_ncand;
  __shared__ double red[5][BLK];                       // 10 KB

  const int tid = threadIdx.x;

  if (tid == 0) { s_npos = 0; s_ntargs = 0; s_first = 0; s_B = 0; s_ncand = 0; }
  hist[tid] = 0;
  if (tid < 16) validw[tid] = 0;
  __syncthreads();

  // ---- load conf -> keys (LDS), histogram of conf in [0.5,1), n_pos ----
  int cpos = 0;
  for (int i = tid; i < NPRED; i += BLK) {
    float c = P[i * 5 + 0];
    cpos += (c > 0.5f) ? 1 : 0;
    uint32_t cb = __float_as_uint(c);
    keys[i] = ((uint64_t)(~cb) << 32) | (uint32_t)i;   // ascending key == conf desc, idx asc
    if (cb >= 0x3F000000u && cb < 0x3F800000u)
      atomicAdd(&hist[(cb >> 15) & 0xFF], 1);
  }
  atomicAdd(&s_npos, cpos);

  // ---- stage targets + validity bits + n_targs ----
  int ct = 0;
  for (int m = tid; m < MT; m += BLK) {
    float tp = T[m * 5 + 0];
    if (tp == 1.0f) { ct++; atomicOr(&validw[m >> 5], 1u << (m & 31)); }
    tgx[m] = T[m * 5 + 1];
    tgy[m] = T[m * 5 + 2];
    tga[m] = T[m * 5 + 3];
    tgb[m] = T[m * 5 + 4];
  }
  atomicAdd(&s_ntargs, ct);
  __syncthreads();
  const int n_pos = s_npos;
  const int n_targs = s_ntargs;

  // ---- wave0: suffix-scan histogram, find cutoff bucket B ----
  if (tid < 64) {
    const int lane = tid;
    int4 h4 = *reinterpret_cast<const int4*>(&hist[lane * 4]);
    int t = h4.x + h4.y + h4.z + h4.w;
    int S = t;  // inclusive suffix over lanes [lane..63]
#pragma unroll
    for (int off = 1; off < 64; off <<= 1) {
      int o = __shfl_down(S, off);
      if (lane + off < 64) S += o;
    }
    int Snext = S - t;
    int s3 = h4.w + Snext;
    int s2 = h4.z + s3;
    int s1 = h4.y + s2;
    int s0 = h4.x + s1;
    int localB = -1;
    if      (s3 >= n_targs) localB = lane * 4 + 3;
    else if (s2 >= n_targs) localB = lane * 4 + 2;
    else if (s1 >= n_targs) localB = lane * 4 + 1;
    else if (s0 >= n_targs) localB = lane * 4 + 0;
    uint64_t q = __ballot(localB >= 0);
    if (q) {
      int hl = 63 - __clzll((long long)q);
      int B = __builtin_amdgcn_readlane(localB, hl);
      if (lane == 0) s_B = B;
    }
  }
  __syncthreads();
  const int B = s_B;

  // ---- gather candidates (bucket >= B) ----
  for (int i = tid; i < NPRED; i += BLK) {
    uint64_t k = keys[i];
    uint32_t cb = ~(uint32_t)(k >> 32);
    if (cb >= 0x3F000000u && cb < 0x3F800000u && (int)((cb >> 15) & 0xFF) >= B) {
      int slot = atomicAdd(&s_ncand, 1);
      if (slot < NCAND) cand[slot] = k;
    }
  }
  __syncthreads();
  int ncand = min(s_ncand, NCAND);
  for (int i = ncand + tid; i < NCAND; i += BLK) cand[i] = ~0ull;
  __syncthreads();

  // ---- bitonic sort 512 candidates (ascending = conf desc) ----
  for (int k2 = 2; k2 <= NCAND; k2 <<= 1) {
    for (int j = k2 >> 1; j > 0; j >>= 1) {
      int i = ((tid & ~(j - 1)) << 1) | (tid & (j - 1));
      int p = i | j;
      uint64_t a = cand[i], c2 = cand[p];
      bool up = ((i & k2) == 0);
      if ((a > c2) == up) { cand[i] = c2; cand[p] = a; }
      __syncthreads();
    }
  }

  // ---- stage sorted-pred rows for i < n_targs ----
  for (int i = tid; i < n_targs; i += BLK) {
    int idx = (int)(cand[i] & 0xFFFFFFFFu);
    spx[i] = P[idx * 5 + 1];
    spy[i] = P[idx * 5 + 2];
    spa[i] = P[idx * 5 + 3];
    spb[i] = P[idx * 5 + 4];
  }
  uint64_t thrkey = (n_targs > 0) ? cand[n_targs - 1] : 0ull;
  __syncthreads();

  const int K = min(n_pos, n_targs);
  float maccx = 0.f, maccy = 0.f, macca = 0.f, maccb = 0.f;
  float accp = 0.f;
  const float INF = __int_as_float(0x7F800000);

  if (tid < 64) {
    // ---- wave0: greedy matching with DPP argmin ----
    const int lane = tid;
    float txr[8], tyr[8];
    uint32_t okm;  // valid & ~used, 8 bits
    {
      uint32_t w = validw[lane >> 2];
      okm = (w >> ((lane & 3) * 8)) & 0xFFu;
    }
#pragma unroll
    for (int j = 0; j < 8; ++j) { txr[j] = tgx[lane * 8 + j]; tyr[j] = tgy[lane * 8 + j]; }

    float x = spx[0], y = spy[0];
    for (int i = 0; i < K; ++i) {
      int ip = min(i + 1, NCAND - 1);
      float xn = spx[ip], yn = spy[ip];   // prefetch next pred
      float d2m[8];
#pragma unroll
      for (int j = 0; j < 8; ++j) {
        float dx = __fsub_rn(txr[j], x);
        float dy = __fsub_rn(tyr[j], y);
        float d2 = __fadd_rn(__fmul_rn(dx, dx), __fmul_rn(dy, dy));
        d2m[j] = ((okm >> j) & 1u) ? d2 : INF;
      }
      float lmin = fminf(fminf(fminf(d2m[0], d2m[1]), fminf(d2m[2], d2m[3])),
                         fminf(fminf(d2m[4], d2m[5]), fminf(d2m[6], d2m[7])));
      float g = wave_min_f32(lmin);
      int jb = 7;
#pragma unroll
      for (int j = 6; j >= 0; --j) jb = (d2m[j] == g) ? j : jb;
      uint64_t bal = __ballot(lmin == g);
      int src = __ffsll((unsigned long long)bal) - 1;   // lowest lane = lowest target idx
      int m = __builtin_amdgcn_readlane(lane * 8 + jb, src);
      okm &= ~((lane == src) ? (1u << jb) : 0u);

      // accumulate (uniform across lanes; only lane0's copy kept)
      float tx = tgx[m], ty = tgy[m], ta = tga[m], tb = tgb[m];
      float pa = spa[i], pb = spb[i];
      float dx = __fsub_rn(x, tx);
      float dy = __fsub_rn(y, ty);
      float da = __fsub_rn(pa, ta);
      float db = __fsub_rn(pb, tb);
      maccx += __fmul_rn(dx, dx);
      maccy += __fmul_rn(dy, dy);
      macca += __fmul_rn(da, da);
      maccb += __fmul_rn(db, db);

      x = xn; y = yn;
    }
    // first valid unused target
    uint32_t fi = okm ? (uint32_t)(lane * 8 + __ffs(okm) - 1) : 0xFFFFFFFFu;
    fi = wave_min_u32(fi);
    if (lane == 0) s_first = (fi < MT) ? (int)fi : 0;
  } else {
    // ---- waves 1-3: prob loss over all preds (t = key <= thrkey) ----
    for (int i = tid - 64; i < NPRED; i += (BLK - 64)) {
      uint64_t k = keys[i];
      float p = __uint_as_float(~(uint32_t)(k >> 32));
      bool tpos = (k <= thrkey);
      accp += tpos ? -fmaxf(logf(p), -100.0f)
                   : -fmaxf(log1pf(-p), -100.0f);
    }
  }
  if (tid != 0) { maccx = 0.f; maccy = 0.f; macca = 0.f; maccb = 0.f; }
  __syncthreads();

  // ---- case_first window [n_pos, n_targs) ----
  if (n_pos < n_targs) {
    int f = s_first;
    float fx = tgx[f], fy = tgy[f], fa = tga[f], fb = tgb[f];
    for (int i = n_pos + tid; i < n_targs; i += BLK) {
      float dx = __fsub_rn(spx[i], fx);
      float dy = __fsub_rn(spy[i], fy);
      float da = __fsub_rn(spa[i], fa);
      float db = __fsub_rn(spb[i], fb);
      maccx += __fmul_rn(dx, dx);
      maccy += __fmul_rn(dy, dy);
      macca += __fmul_rn(da, da);
      maccb += __fmul_rn(db, db);
    }
  }

  // ---- block reduce (doubles) + global atomic ----
  red[0][tid] = (double)maccx;
  red[1][tid] = (double)maccy;
  red[2][tid] = (double)macca;
  red[3][tid] = (double)maccb;
  red[4][tid] = (double)accp;
  __syncthreads();
  for (int s = BLK / 2; s > 0; s >>= 1) {
    if (tid < s) {
#pragma unroll
      for (int c = 0; c < 5; ++c) red[c][tid] += red[c][tid + s];
    }
    __syncthreads();
  }
  if (tid == 0) {
#pragma unroll
    for (int c = 0; c < 5; ++c) atomicAdd(&acc[c], red[c][0]);
  }
}

__global__ void finalize_kernel(const double* __restrict__ acc,
                                float* __restrict__ out, double inv) {
  int c = threadIdx.x;
  if (c < 5) out[c] = (float)(acc[c] * inv);
}

extern "C" void kernel_launch(void* const* d_in, const int* in_sizes, int n_in,
                              void* d_out, int out_size, void* d_ws, size_t ws_size,
                              hipStream_t stream) {
  const float* preds = (const float*)d_in[0];
  const float* targets = (const float*)d_in[1];
  int B = in_sizes[0] / (NPRED * 5);

  double* acc = (double*)d_ws;
  hipMemsetAsync(acc, 0, 5 * sizeof(double), stream);
  loss_kernel<<<B, BLK, 0, stream>>>(preds, targets, acc);
  finalize_kernel<<<1, 64, 0, stream>>>(acc, (float*)d_out,
                                        1.0 / ((double)B * NPRED));
}